// Round 1
// baseline (235.796 us; speedup 1.0000x reference)
//
#include <hip/hip_runtime.h>
#include <hip/hip_bf16.h>
#include <hip/hip_fp16.h>

// Problem constants (match reference)
#define B_     8
#define L_     4096
#define DIN    256
#define DOUT   256
#define NGATE  1536   // 3*DOUT*2 dirs
#define KDIM   768    // 3*DIN (im2col window)
#define LP     (L_ + 2)
#define CHUNK  32
#define NCHUNK (L_ / CHUNK)
#define NKSTEP (KDIM / 64)   // 12 K-steps of BK=64

typedef short    short8  __attribute__((ext_vector_type(8)));
typedef __bf16   bf16x8  __attribute__((ext_vector_type(8)));
typedef float    floatx4 __attribute__((ext_vector_type(4)));
typedef _Float16 half4   __attribute__((ext_vector_type(4)));

__device__ __forceinline__ float fast_sigmoid(float x) {
    return __builtin_amdgcn_rcpf(1.f + __expf(-x));
}
__device__ __forceinline__ float fast_tanh(float x) {
    return 1.f - 2.f * __builtin_amdgcn_rcpf(1.f + __expf(2.f * x));
}
__device__ __forceinline__ unsigned short f2bf(float x) {
    unsigned u = __float_as_uint(x);
    u += 0x7FFF + ((u >> 16) & 1);   // RNE
    return (unsigned short)(u >> 16);
}
// Async global->LDS, 16B per lane. LDS dest = wave-uniform base + lane*16.
__device__ __forceinline__ void gload16(const unsigned short* g, unsigned short* l) {
    __builtin_amdgcn_global_load_lds((const __attribute__((address_space(1))) void*)g,
                                     (__attribute__((address_space(3))) void*)l,
                                     16, 0, 0);
}

// Native-layout gates addressing ------------------------------------------
// 256x256-tile 8-wave (2M x 4N) MFMA C-layout, fp16 flat unit index:
//   idx = (bm*6 + nblk)*65536 + (wr*4+wcl)*8192 + (ni*8+mi)*256
//       + (quad*16 + l16)*4 + rr
// For batch b, time t, gate column n (n in [0,1536)):
//   bm = b*16 + (t>>8); tt = t&255: mh=tt>>7, wr=(tt>>6)&1, mlo=(tt>>4)&3,
//   quad=(tt>>2)&3, rr=t&3; mi = mh*4+mlo
//   nblk = n>>8; nn = n&255: nh=nn>>7, wcl=(nn>>5)&3, nlo=(nn>>4)&1, l16=n&15;
//   ni = nh*2+nlo
// rr has stride 1, so half4 loads over 4 consecutive t still work.
__device__ __forceinline__ int gate_noff(int n) {
    return (n >> 8) * 65536 + ((n >> 5) & 3) * 8192
         + (((n >> 7) & 1) * 2 + ((n >> 4) & 1)) * 2048 + (n & 15) * 4;
}
__device__ __forceinline__ int gate_toff(int b, int t) {
    return (b * 16 + (t >> 8)) * 393216 + ((t >> 6) & 1) * 32768
         + (((t >> 7) & 1) * 4 + ((t >> 4) & 3)) * 256 + ((t >> 2) & 3) * 64;
}

// ---------------------------------------------------------------------------
// prep_all: fused prep_x (blocks [0,NXB)) + prep_w (blocks [NXB,..)).
#define NXB ((B_ * LP * 64 + 255) / 256)
#define NWB ((NGATE * KDIM + 255) / 256)
__global__ void prep_all(const float* __restrict__ x, unsigned short* __restrict__ Xp,
                         const float* __restrict__ Wf, const float* __restrict__ bf_,
                         const float* __restrict__ Wb, const float* __restrict__ bb,
                         unsigned short* __restrict__ Wc, float* __restrict__ bc) {
    if (blockIdx.x < NXB) {
        int idx = blockIdx.x * 256 + threadIdx.x;
        int row = idx >> 6;
        if (row >= B_ * LP) return;
        int c4 = (idx & 63) << 2;
        int b = row / LP, r = row - b * LP;
        float4 v = make_float4(0.f, 0.f, 0.f, 0.f);
        if (r >= 1 && r <= L_) {
            v = *(const float4*)(x + ((size_t)(b * L_ + (r - 1))) * DIN + c4);
        }
        ushort4 o = make_ushort4(f2bf(v.x), f2bf(v.y), f2bf(v.z), f2bf(v.w));
        *(ushort4*)(Xp + (size_t)row * DIN + c4) = o;
    } else {
        int gid = (blockIdx.x - NXB) * 256 + threadIdx.x;
        if (gid < NGATE) {
            bc[gid] = (gid < 768) ? bf_[gid] : bb[gid - 768];
        }
        if (gid >= NGATE * KDIM) return;
        int n = gid / KDIM, k = gid - n * KDIM;
        int s = k >> 8, ic = k & 255;
        const float* W = (n < 768) ? Wf : Wb;
        int oc = (n < 768) ? n : n - 768;
        float v = W[(size_t)oc * KDIM + ic * 3 + s];
        Wc[(size_t)n * KDIM + k] = f2bf(v);
    }
}

// ---------------------------------------------------------------------------
// gemm_gates: 256x256 tile, 512 threads (8 waves = 2M x 4N), BK=64,
// 16x16x32 bf16 MFMA, 8-phase schedule (4 phases per K-step, 2 K-steps per
// LDS double-buffer cycle) with counted vmcnt(4) — never a full drain in the
// main loop. LDS 128 KiB: As[2][256x64] + Bs[2][256x64], XOR-swizzled via
// pre-swizzled global source addresses (linear global_load_lds dest).
//
// Phase read-quadrants: p1(A0,B0) p2(A1,B0) p3(A0,B1) p4(A1,B1).
// Stage schedule (half-tiles, 2 gload16/thread each):
//   p1: A1(k+1)->buf^1   p2: B1(k+1)->buf^1   p3: B0(k+2)->buf   p4: A0(k+2)->buf
// Safety: each half is fully read (lgkmcnt(0)+barrier) strictly before the
// stage that overwrites it is issued; vmcnt(4) at p4 guarantees all of
// K-step k+1 has landed while leaving the two p3/p4 half-tiles in flight.
__launch_bounds__(512, 2)
__global__ void gemm_gates(const unsigned short* __restrict__ Xp,
                           const unsigned short* __restrict__ Wc,
                           const float* __restrict__ bc,
                           _Float16* __restrict__ gates) {
    __shared__ alignas(16) unsigned short As[2][16384];   // 64 KB
    __shared__ alignas(16) unsigned short Bs[2][16384];   // 64 KB
    const int tid  = threadIdx.x;
    const int lane = tid & 63, w = tid >> 6;        // wave 0..7
    const int quad = lane >> 4, l16 = lane & 15;
    const int wr = w >> 2, wcl = w & 3;             // wr 0..1 (m), wcl 0..3 (n)

    int flat = blockIdx.x;                 // 0..767
    int xcd  = flat & 7;
    int slot = flat >> 3;                  // 0..95
    int bm   = xcd * 16 + slot / 6;        // 0..127 m-tile (256 rows each)
    int nblk = slot % 6;                   // 0..5   n-tile (256 cols each)
    const int b  = bm >> 4;
    const int t0 = (bm & 15) << 8;
    const int n0 = nblk << 8;
    const unsigned short* Ab = Xp + (size_t)b * LP * DIN;

    // Per-lane inverse-swizzle source mapping for one 128x64 half-tile
    // (identical for A and B halves; constant across K-steps).
    int rS[2], cgS[2];
#pragma unroll
    for (int j = 0; j < 2; j++) {
        int G = (j * 8 + w) * 64 + lane;         // granule 0..1023
        rS[j]  = G >> 3;                         // local row 0..127
        cgS[j] = ((G & 7) ^ (rS[j] & 7)) * 8;    // swizzled column (shorts)
    }

    floatx4 acc[8][4];
#pragma unroll
    for (int i = 0; i < 8; i++)
#pragma unroll
        for (int j = 0; j < 4; j++) acc[i][j] = (floatx4)0.f;

#define STAGE_A(ks, mh, cb) do {                                               \
    const int sh_ = (ks) >> 2, c0_ = ((ks) & 3) * 64;                          \
    _Pragma("unroll")                                                          \
    for (int j_ = 0; j_ < 2; ++j_)                                             \
        gload16(Ab + (size_t)(t0 + (mh) * 128 + rS[j_] + sh_) * DIN + c0_ + cgS[j_], \
                &As[cb][(mh) * 8192 + (j_ * 8 + w) * 512]);                    \
} while (0)

#define STAGE_B(ks, nh, cb) do {                                               \
    const int k0_ = (ks) * 64;                                                 \
    _Pragma("unroll")                                                          \
    for (int j_ = 0; j_ < 2; ++j_)                                             \
        gload16(Wc + (size_t)(n0 + (nh) * 128 + rS[j_]) * KDIM + k0_ + cgS[j_], \
                &Bs[cb][(nh) * 8192 + (j_ * 8 + w) * 512]);                    \
} while (0)

#define PHASE(mh, nh, cb, STG) do {                                            \
    short8 afr[4][2], bfr[2][2];                                               \
    _Pragma("unroll")                                                          \
    for (int m_ = 0; m_ < 4; ++m_) {                                           \
        const int R = (mh) * 128 + wr * 64 + m_ * 16 + l16;                    \
        const int rx = R & 7;                                                  \
        afr[m_][0] = *(const short8*)&As[cb][R * 64 + ((quad ^ rx) << 3)];     \
        afr[m_][1] = *(const short8*)&As[cb][R * 64 + (((4 + quad) ^ rx) << 3)]; \
    }                                                                          \
    _Pragma("unroll")                                                          \
    for (int n_ = 0; n_ < 2; ++n_) {                                           \
        const int R = (nh) * 128 + wcl * 32 + n_ * 16 + l16;                   \
        const int rx = R & 7;                                                  \
        bfr[n_][0] = *(const short8*)&Bs[cb][R * 64 + ((quad ^ rx) << 3)];     \
        bfr[n_][1] = *(const short8*)&Bs[cb][R * 64 + (((4 + quad) ^ rx) << 3)]; \
    }                                                                          \
    STG;                                                                       \
    __builtin_amdgcn_s_barrier();                                              \
    asm volatile("s_waitcnt lgkmcnt(0)" ::: "memory");                         \
    __builtin_amdgcn_s_setprio(1);                                             \
    _Pragma("unroll")                                                          \
    for (int m_ = 0; m_ < 4; ++m_)                                             \
    _Pragma("unroll")                                                          \
    for (int n_ = 0; n_ < 2; ++n_) {                                           \
        acc[(mh)*4 + m_][(nh)*2 + n_] = __builtin_amdgcn_mfma_f32_16x16x32_bf16( \
            __builtin_bit_cast(bf16x8, afr[m_][0]),                            \
            __builtin_bit_cast(bf16x8, bfr[n_][0]),                            \
            acc[(mh)*4 + m_][(nh)*2 + n_], 0, 0, 0);                           \
        acc[(mh)*4 + m_][(nh)*2 + n_] = __builtin_amdgcn_mfma_f32_16x16x32_bf16( \
            __builtin_bit_cast(bf16x8, afr[m_][1]),                            \
            __builtin_bit_cast(bf16x8, bfr[n_][1]),                            \
            acc[(mh)*4 + m_][(nh)*2 + n_], 0, 0, 0);                           \
    }                                                                          \
    __builtin_amdgcn_s_setprio(0);                                             \
} while (0)

#define WINDOW(kv, cb, nb) do {                                                \
    const int k_ = (kv);                                                       \
    PHASE(0, 0, cb, { if (k_ + 1 < NKSTEP) STAGE_A(k_ + 1, 1, nb); });         \
    __builtin_amdgcn_s_barrier();                                              \
    PHASE(1, 0, cb, { if (k_ + 1 < NKSTEP) STAGE_B(k_ + 1, 1, nb); });         \
    __builtin_amdgcn_s_barrier();                                              \
    PHASE(0, 1, cb, { if (k_ + 2 < NKSTEP) STAGE_B(k_ + 2, 0, cb); });         \
    __builtin_amdgcn_s_barrier();                                              \
    PHASE(1, 1, cb, { if (k_ + 2 < NKSTEP) STAGE_A(k_ + 2, 0, cb); });         \
    if (k_ + 2 < NKSTEP) { asm volatile("s_waitcnt vmcnt(4)" ::: "memory"); }  \
    else                 { asm volatile("s_waitcnt vmcnt(0)" ::: "memory"); }  \
    __builtin_amdgcn_s_barrier();                                              \
} while (0)

    // Prologue: K-step 0 (4 halves) + A0/B0 of K-step 1; wait for K-step 0
    // only (vmcnt(4) leaves the two K1 halves in flight).
    STAGE_A(0, 0, 0); STAGE_B(0, 0, 0); STAGE_A(0, 1, 0); STAGE_B(0, 1, 0);
    STAGE_A(1, 0, 1); STAGE_B(1, 0, 1);
    asm volatile("s_waitcnt vmcnt(4)" ::: "memory");
    __builtin_amdgcn_s_barrier();

    for (int kp = 0; kp < NKSTEP / 2; ++kp) {
        WINDOW(2 * kp,     0, 1);
        WINDOW(2 * kp + 1, 1, 0);
    }

#undef WINDOW
#undef PHASE
#undef STAGE_B
#undef STAGE_A

    // Epilogue: bias + activation, native-layout 8B stores (512B/wave/instr).
    const int cls = nblk % 3;                      // 0=f,1=o,2=z (wave-uniform)
    _Float16* gb = gates + ((size_t)((bm * 6 + nblk) * 8 + w)) * 8192 + lane * 4;
#pragma unroll
    for (int ni = 0; ni < 4; ++ni) {
        const float bias = bc[n0 + (ni >> 1) * 128 + wcl * 32 + (ni & 1) * 16 + l16];
#pragma unroll
        for (int mi = 0; mi < 8; ++mi) {
            half4 hv;
#pragma unroll
            for (int rr = 0; rr < 4; ++rr) {
                float v = acc[mi][ni][rr] + bias;
                v = (cls == 2) ? fast_tanh(v) : fast_sigmoid(v);
                hv[rr] = (_Float16)v;
            }
            *(half4*)(gb + (ni * 8 + mi) * 256) = hv;
        }
    }
}

// ---------------------------------------------------------------------------
// scan_chunks (phase A): thread = one channel, block = one (chunk,b,dir).
// Reads f,z in native layout (8B = 4 consecutive t per load), composes the
// chunk affine map c_out = P*c_in + W.
__global__ void scan_chunks(const _Float16* __restrict__ gates,
                            float2* __restrict__ PW) {
    const int d = threadIdx.x;                       // channel 0..255
    const int s = blockIdx.x, b = blockIdx.y, dir = blockIdx.z;
    const int onf = gate_noff(dir * 768 + d);
    const int onz = gate_noff(dir * 768 + 512 + d);
    float P = 1.f, W = 0.f;
    if (dir == 0) {
#pragma unroll
        for (int gi = 0; gi < 8; gi++) {
            int t = s * CHUNK + gi * 4;
            int ot = gate_toff(b, t);
            half4 f4 = *(const half4*)(gates + ot + onf);
            half4 z4 = *(const half4*)(gates + ot + onz);
#pragma unroll
            for (int u = 0; u < 4; u++) {
                float f = (float)f4[u], z = (float)z4[u];
                W = f * W + (1.f - f) * z;
                P *= f;
            }
        }
    } else {
#pragma unroll
        for (int gi = 7; gi >= 0; gi--) {
            int t = s * CHUNK + gi * 4;
            int ot = gate_toff(b, t);
            half4 f4 = *(const half4*)(gates + ot + onf);
            half4 z4 = *(const half4*)(gates + ot + onz);
#pragma unroll
            for (int u = 3; u >= 0; u--) {
                float f = (float)f4[u], z = (float)z4[u];
                W = f * W + (1.f - f) * z;
                P *= f;
            }
        }
    }
    PW[(((size_t)(dir * 8 + b)) * NCHUNK + s) * 256 + d] = make_float2(P, W);
}

// ---------------------------------------------------------------------------
// scan_seq (phase B): sequential scan over NCHUNK=128 chunks.
__global__ void scan_seq(const float2* __restrict__ PW, float* __restrict__ C0) {
    const int c = threadIdx.x;
    const int dir = blockIdx.x >> 3, b = blockIdx.x & 7;
    const size_t base = ((size_t)(dir * 8 + b)) * NCHUNK * 256 + c;
    float cc = 0.f;
    if (dir == 0) {
#pragma unroll 16
        for (int s = 0; s < NCHUNK; s++) {
            float2 pw = PW[base + (size_t)s * 256];
            C0[base + (size_t)s * 256] = cc;
            cc = pw.x * cc + pw.y;
        }
    } else {
#pragma unroll 16
        for (int s = NCHUNK - 1; s >= 0; s--) {
            float2 pw = PW[base + (size_t)s * 256];
            C0[base + (size_t)s * 256] = cc;
            cc = pw.x * cc + pw.y;
        }
    }
}

// ---------------------------------------------------------------------------
// scan_final (phase C): thread = one channel, block = one (chunk,b,dir).
// Replays the chunk from C0; h values round-trip through a 4KB LDS tile per
// 4-t group so the global store is [t][ch]-contiguous float4 per lane.
__global__ void scan_final(const _Float16* __restrict__ gates,
                           const float* __restrict__ C0,
                           float* __restrict__ out) {
    __shared__ float hbuf[4][256];
    const int d = threadIdx.x;
    const int s = blockIdx.x, b = blockIdx.y, dir = blockIdx.z;
    const int onf = gate_noff(dir * 768 + d);
    const int ono = gate_noff(dir * 768 + 256 + d);
    const int onz = gate_noff(dir * 768 + 512 + d);
    float c = C0[(((size_t)(dir * 8 + b)) * NCHUNK + s) * 256 + d];
    float* ob = out + (size_t)(b * L_) * (2 * DOUT) + dir * DOUT;
    float* lasth = out + (size_t)B_ * L_ * (2 * DOUT);
    float* lastc = lasth + B_ * (2 * DOUT);
    const int tl = d >> 6, cl = (d & 63) * 4;    // output-store mapping

    for (int gg = 0; gg < 8; gg++) {
        int gi = (dir == 0) ? gg : 7 - gg;
        int t = s * CHUNK + gi * 4;
        int ot = gate_toff(b, t);
        half4 f4 = *(const half4*)(gates + ot + onf);
        half4 o4 = *(const half4*)(gates + ot + ono);
        half4 z4 = *(const half4*)(gates + ot + onz);
        float h[4];
        if (dir == 0) {
#pragma unroll
            for (int u = 0; u < 4; u++) {
                float f = (float)f4[u], z = (float)z4[u];
                c = f * c + (1.f - f) * z;
                h[u] = c * (float)o4[u];
            }
            if (s == NCHUNK - 1 && gi == 7) {
                lasth[b * 2 * DOUT + d] = h[3];
                lastc[b * 2 * DOUT + d] = c;
            }
        } else {
#pragma unroll
            for (int u = 3; u >= 0; u--) {
                float f = (float)f4[u], z = (float)z4[u];
                c = f * c + (1.f - f) * z;
                h[u] = c * (float)o4[u];
                if (u == 3 && s == NCHUNK - 1 && gi == 7) {
                    lasth[b * 2 * DOUT + DOUT + d] = h[3];
                    lastc[b * 2 * DOUT + DOUT + d] = c;
                }
            }
        }
        hbuf[0][d] = h[0];
        hbuf[1][d] = h[1];
        hbuf[2][d] = h[2];
        hbuf[3][d] = h[3];
        __syncthreads();
        *(float4*)&ob[(size_t)(t + tl) * (2 * DOUT) + cl] = *(float4*)&hbuf[tl][cl];
        __syncthreads();
    }
}

// ---------------------------------------------------------------------------
extern "C" void kernel_launch(void* const* d_in, const int* in_sizes, int n_in,
                              void* d_out, int out_size, void* d_ws, size_t ws_size,
                              hipStream_t stream) {
    const float* x   = (const float*)d_in[0];
    // d_in[1] = lengths (unused by the reference computation)
    const float* Wf  = (const float*)d_in[2];
    const float* bfv = (const float*)d_in[3];
    const float* Wb  = (const float*)d_in[4];
    const float* bbv = (const float*)d_in[5];

    char* ws = (char*)d_ws;
    // Workspace layout (bytes):
    //   Xp    bf16  B*(L+2)*256          = 16,785,408   (offset 0; dead after GEMM)
    //   Wc    bf16  1536*768             =  2,359,296   (offset 16,785,408)
    //   bc    f32   1536                 =      6,144   (offset 19,144,704)
    //   gates fp16  B*L*1536             = 100,663,296  (offset 19,150,848, native layout)
    //   PW    f32x2 2*8*128*256          =  4,194,304   (offset 0 — reuses Xp)
    //   C0    f32   2*8*128*256          =  2,097,152   (offset 4,194,304 — reuses Xp)
    unsigned short* Xp    = (unsigned short*)(ws);
    unsigned short* Wc    = (unsigned short*)(ws + 16785408);
    float*          bc    = (float*)(ws + 19144704);
    _Float16*       gates = (_Float16*)(ws + 19150848);
    float2*         PW    = (float2*)(ws);              // reuse Xp region
    float*          C0    = (float*)(ws + 4194304);     // reuse Xp region
    float*          out   = (float*)d_out;

    prep_all<<<NXB + NWB, 256, 0, stream>>>(x, Xp, Wf, bfv, Wb, bbv, Wc, bc);
    gemm_gates<<<768, 512, 0, stream>>>(Xp, Wc, bc, gates);
    scan_chunks<<<dim3(NCHUNK, B_, 2), 256, 0, stream>>>(gates, PW);
    scan_seq<<<16, 256, 0, stream>>>(PW, C0);
    scan_final<<<dim3(NCHUNK, B_, 2), 256, 0, stream>>>(gates, C0, out);
}

// Round 2
// 222.849 us; speedup vs baseline: 1.0581x; 1.0581x over previous
//
#include <hip/hip_runtime.h>
#include <hip/hip_bf16.h>
#include <hip/hip_fp16.h>

// Problem constants (match reference)
#define B_     8
#define L_     4096
#define DIN    256
#define DOUT   256
#define NGATE  1536   // 3*DOUT*2 dirs
#define KDIM   768    // 3*DIN (im2col window)
#define LP     (L_ + 2)
#define CHUNK  32
#define NCHUNK (L_ / CHUNK)
#define NKSTEP (KDIM / 64)   // 12 K-steps of BK=64

typedef short    short8  __attribute__((ext_vector_type(8)));
typedef __bf16   bf16x8  __attribute__((ext_vector_type(8)));
typedef float    floatx4 __attribute__((ext_vector_type(4)));
typedef _Float16 half4   __attribute__((ext_vector_type(4)));

__device__ __forceinline__ float fast_sigmoid(float x) {
    return __builtin_amdgcn_rcpf(1.f + __expf(-x));
}
__device__ __forceinline__ float fast_tanh(float x) {
    return 1.f - 2.f * __builtin_amdgcn_rcpf(1.f + __expf(2.f * x));
}
__device__ __forceinline__ unsigned short f2bf(float x) {
    unsigned u = __float_as_uint(x);
    u += 0x7FFF + ((u >> 16) & 1);   // RNE
    return (unsigned short)(u >> 16);
}
// Async global->LDS, 16B per lane. LDS dest = wave-uniform base + lane*16.
__device__ __forceinline__ void gload16(const unsigned short* g, unsigned short* l) {
    __builtin_amdgcn_global_load_lds((const __attribute__((address_space(1))) void*)g,
                                     (__attribute__((address_space(3))) void*)l,
                                     16, 0, 0);
}

// Native-layout gates addressing ------------------------------------------
// 256x256-tile 8-wave (2M x 4N) MFMA C-layout, fp16 flat unit index:
//   idx = (bm*6 + nblk)*65536 + (wr*4+wcl)*8192 + (ni*8+mi)*256
//       + (quad*16 + l16)*4 + rr
// For batch b, time t, gate column n (n in [0,1536)):
//   bm = b*16 + (t>>8); tt = t&255: mh=tt>>7, wr=(tt>>6)&1, mlo=(tt>>4)&3,
//   quad=(tt>>2)&3, rr=t&3; mi = mh*4+mlo
//   nblk = n>>8; nn = n&255: nh=nn>>7, wcl=(nn>>5)&3, nlo=(nn>>4)&1, l16=n&15;
//   ni = nh*2+nlo
// rr has stride 1, so half4 loads over 4 consecutive t still work.
__device__ __forceinline__ int gate_noff(int n) {
    return (n >> 8) * 65536 + ((n >> 5) & 3) * 8192
         + (((n >> 7) & 1) * 2 + ((n >> 4) & 1)) * 2048 + (n & 15) * 4;
}
__device__ __forceinline__ int gate_toff(int b, int t) {
    return (b * 16 + (t >> 8)) * 393216 + ((t >> 6) & 1) * 32768
         + (((t >> 7) & 1) * 4 + ((t >> 4) & 3)) * 256 + ((t >> 2) & 3) * 64;
}

// ---------------------------------------------------------------------------
// prep_all: fused prep_x (blocks [0,NXB)) + prep_w (blocks [NXB,..)).
#define NXB ((B_ * LP * 64 + 255) / 256)
#define NWB ((NGATE * KDIM + 255) / 256)
__global__ void prep_all(const float* __restrict__ x, unsigned short* __restrict__ Xp,
                         const float* __restrict__ Wf, const float* __restrict__ bf_,
                         const float* __restrict__ Wb, const float* __restrict__ bb,
                         unsigned short* __restrict__ Wc, float* __restrict__ bc) {
    if (blockIdx.x < NXB) {
        int idx = blockIdx.x * 256 + threadIdx.x;
        int row = idx >> 6;
        if (row >= B_ * LP) return;
        int c4 = (idx & 63) << 2;
        int b = row / LP, r = row - b * LP;
        float4 v = make_float4(0.f, 0.f, 0.f, 0.f);
        if (r >= 1 && r <= L_) {
            v = *(const float4*)(x + ((size_t)(b * L_ + (r - 1))) * DIN + c4);
        }
        ushort4 o = make_ushort4(f2bf(v.x), f2bf(v.y), f2bf(v.z), f2bf(v.w));
        *(ushort4*)(Xp + (size_t)row * DIN + c4) = o;
    } else {
        int gid = (blockIdx.x - NXB) * 256 + threadIdx.x;
        if (gid < NGATE) {
            bc[gid] = (gid < 768) ? bf_[gid] : bb[gid - 768];
        }
        if (gid >= NGATE * KDIM) return;
        int n = gid / KDIM, k = gid - n * KDIM;
        int s = k >> 8, ic = k & 255;
        const float* W = (n < 768) ? Wf : Wb;
        int oc = (n < 768) ? n : n - 768;
        float v = W[(size_t)oc * KDIM + ic * 3 + s];
        Wc[(size_t)n * KDIM + k] = f2bf(v);
    }
}

// ---------------------------------------------------------------------------
// gemm_gates: 256x256 tile, 512 threads (8 waves = 2M x 4N), BK=64,
// 16x16x32 bf16 MFMA, 4 phases per K-step with counted vmcnt(4) and
// register-held fragments (each LDS fragment read ONCE per K-step):
//   p1: read A0(8xb128)+B0(4xb128), MFMA(A0,B0)   stage A1(k+1)->nb
//   p2: read B1(4xb128),            MFMA(A0,B1)   stage B1(k+1)->nb
//   p3: read A1(8xb128),            MFMA(A1,B0)   stage B0(k+2)->cb
//   p4: (no reads),                 MFMA(A1,B1)   stage A0(k+2)->cb
// 24 ds_read_b128 per wave per K-step (vs 48 if each phase re-read) ->
// LDS read traffic (196KB/CU/K-step) now below the MFMA time (2.46k cyc).
// Overwrite safety: every stage targets a half whose ds_reads completed at
// least one barrier earlier (A0/B0[cb] read p1, staged p3/p4; nb halves read
// in the previous window). vmcnt(4) at window end drains through this
// window's p2 stage => all of K-step k+1 landed; k+2's two halves in flight.
__launch_bounds__(512, 2)
__global__ void gemm_gates(const unsigned short* __restrict__ Xp,
                           const unsigned short* __restrict__ Wc,
                           const float* __restrict__ bc,
                           _Float16* __restrict__ gates) {
    __shared__ alignas(16) unsigned short As[2][16384];   // 64 KB
    __shared__ alignas(16) unsigned short Bs[2][16384];   // 64 KB
    const int tid  = threadIdx.x;
    const int lane = tid & 63, w = tid >> 6;        // wave 0..7
    const int quad = lane >> 4, l16 = lane & 15;
    const int wr = w >> 2, wcl = w & 3;             // wr 0..1 (m), wcl 0..3 (n)

    int flat = blockIdx.x;                 // 0..767
    int xcd  = flat & 7;
    int slot = flat >> 3;                  // 0..95
    int bm   = xcd * 16 + slot / 6;        // 0..127 m-tile (256 rows each)
    int nblk = slot % 6;                   // 0..5   n-tile (256 cols each)
    const int b  = bm >> 4;
    const int t0 = (bm & 15) << 8;
    const int n0 = nblk << 8;
    const unsigned short* Ab = Xp + (size_t)b * LP * DIN;

    // Per-lane inverse-swizzle source mapping for one 128x64 half-tile
    // (identical for A and B halves; constant across K-steps).
    int rS[2], cgS[2];
#pragma unroll
    for (int j = 0; j < 2; j++) {
        int G = (j * 8 + w) * 64 + lane;         // granule 0..1023
        rS[j]  = G >> 3;                         // local row 0..127
        cgS[j] = ((G & 7) ^ (rS[j] & 7)) * 8;    // swizzled column (shorts)
    }

    floatx4 acc[8][4];
#pragma unroll
    for (int i = 0; i < 8; i++)
#pragma unroll
        for (int j = 0; j < 4; j++) acc[i][j] = (floatx4)0.f;

#define STAGE_A(ks, mh, cb) do {                                               \
    const int sh_ = (ks) >> 2, c0_ = ((ks) & 3) * 64;                          \
    _Pragma("unroll")                                                          \
    for (int j_ = 0; j_ < 2; ++j_)                                             \
        gload16(Ab + (size_t)(t0 + (mh) * 128 + rS[j_] + sh_) * DIN + c0_ + cgS[j_], \
                &As[cb][(mh) * 8192 + (j_ * 8 + w) * 512]);                    \
} while (0)

#define STAGE_B(ks, nh, cb) do {                                               \
    const int k0_ = (ks) * 64;                                                 \
    _Pragma("unroll")                                                          \
    for (int j_ = 0; j_ < 2; ++j_)                                             \
        gload16(Wc + (size_t)(n0 + (nh) * 128 + rS[j_]) * KDIM + k0_ + cgS[j_], \
                &Bs[cb][(nh) * 8192 + (j_ * 8 + w) * 512]);                    \
} while (0)

#define DSREAD_A(dst, mh, cb) do {                                             \
    _Pragma("unroll")                                                          \
    for (int m_ = 0; m_ < 4; ++m_) {                                           \
        const int R = (mh) * 128 + wr * 64 + m_ * 16 + l16;                    \
        const int rx = R & 7;                                                  \
        dst[m_][0] = *(const short8*)&As[cb][R * 64 + ((quad ^ rx) << 3)];     \
        dst[m_][1] = *(const short8*)&As[cb][R * 64 + (((4 + quad) ^ rx) << 3)]; \
    }                                                                          \
} while (0)

#define DSREAD_B(dst, nh, cb) do {                                             \
    _Pragma("unroll")                                                          \
    for (int n_ = 0; n_ < 2; ++n_) {                                           \
        const int R = (nh) * 128 + wcl * 32 + n_ * 16 + l16;                   \
        const int rx = R & 7;                                                  \
        dst[n_][0] = *(const short8*)&Bs[cb][R * 64 + ((quad ^ rx) << 3)];     \
        dst[n_][1] = *(const short8*)&Bs[cb][R * 64 + (((4 + quad) ^ rx) << 3)]; \
    }                                                                          \
} while (0)

#define MFMA16(ah, bh, mh, nh)                                                 \
    _Pragma("unroll")                                                          \
    for (int m_ = 0; m_ < 4; ++m_)                                             \
    _Pragma("unroll")                                                          \
    for (int n_ = 0; n_ < 2; ++n_) {                                           \
        acc[(mh)*4 + m_][(nh)*2 + n_] = __builtin_amdgcn_mfma_f32_16x16x32_bf16( \
            __builtin_bit_cast(bf16x8, ah[m_][0]),                             \
            __builtin_bit_cast(bf16x8, bh[n_][0]),                             \
            acc[(mh)*4 + m_][(nh)*2 + n_], 0, 0, 0);                           \
        acc[(mh)*4 + m_][(nh)*2 + n_] = __builtin_amdgcn_mfma_f32_16x16x32_bf16( \
            __builtin_bit_cast(bf16x8, ah[m_][1]),                             \
            __builtin_bit_cast(bf16x8, bh[n_][1]),                             \
            acc[(mh)*4 + m_][(nh)*2 + n_], 0, 0, 0);                           \
    }

#define WINDOW(kv, cb, nb) do {                                                \
    const int k_ = (kv);                                                       \
    short8 a0[4][2], a1[4][2], b0[2][2], b1[2][2];                             \
    /* p1: read A0,B0; compute (A0,B0); stage A1(k+1)->nb */                   \
    DSREAD_A(a0, 0, cb); DSREAD_B(b0, 0, cb);                                  \
    if (k_ + 1 < NKSTEP) STAGE_A(k_ + 1, 1, nb);                               \
    __builtin_amdgcn_s_barrier();                                              \
    asm volatile("s_waitcnt lgkmcnt(0)" ::: "memory");                         \
    __builtin_amdgcn_s_setprio(1); MFMA16(a0, b0, 0, 0);                       \
    __builtin_amdgcn_s_setprio(0);                                             \
    __builtin_amdgcn_s_barrier();                                              \
    /* p2: read B1; compute (A0,B1); stage B1(k+1)->nb */                      \
    DSREAD_B(b1, 1, cb);                                                       \
    if (k_ + 1 < NKSTEP) STAGE_B(k_ + 1, 1, nb);                               \
    __builtin_amdgcn_s_barrier();                                              \
    asm volatile("s_waitcnt lgkmcnt(0)" ::: "memory");                         \
    __builtin_amdgcn_s_setprio(1); MFMA16(a0, b1, 0, 1);                       \
    __builtin_amdgcn_s_setprio(0);                                             \
    __builtin_amdgcn_s_barrier();                                              \
    /* p3: read A1; compute (A1,B0); stage B0(k+2)->cb */                      \
    DSREAD_A(a1, 1, cb);                                                       \
    if (k_ + 2 < NKSTEP) STAGE_B(k_ + 2, 0, cb);                               \
    __builtin_amdgcn_s_barrier();                                              \
    asm volatile("s_waitcnt lgkmcnt(0)" ::: "memory");                         \
    __builtin_amdgcn_s_setprio(1); MFMA16(a1, b0, 1, 0);                       \
    __builtin_amdgcn_s_setprio(0);                                             \
    __builtin_amdgcn_s_barrier();                                              \
    /* p4: compute (A1,B1); stage A0(k+2)->cb */                               \
    if (k_ + 2 < NKSTEP) STAGE_A(k_ + 2, 0, cb);                               \
    __builtin_amdgcn_s_barrier();                                              \
    __builtin_amdgcn_s_setprio(1); MFMA16(a1, b1, 1, 1);                       \
    __builtin_amdgcn_s_setprio(0);                                             \
    if (k_ + 2 < NKSTEP) { asm volatile("s_waitcnt vmcnt(4)" ::: "memory"); }  \
    else                 { asm volatile("s_waitcnt vmcnt(0)" ::: "memory"); }  \
    __builtin_amdgcn_s_barrier();                                              \
} while (0)

    // Prologue: K-step 0 (4 halves) + A0/B0 of K-step 1; wait for K-step 0
    // only (vmcnt(4) leaves the two K1 halves in flight).
    STAGE_A(0, 0, 0); STAGE_B(0, 0, 0); STAGE_A(0, 1, 0); STAGE_B(0, 1, 0);
    STAGE_A(1, 0, 1); STAGE_B(1, 0, 1);
    asm volatile("s_waitcnt vmcnt(4)" ::: "memory");
    __builtin_amdgcn_s_barrier();

    for (int kp = 0; kp < NKSTEP / 2; ++kp) {
        WINDOW(2 * kp,     0, 1);
        WINDOW(2 * kp + 1, 1, 0);
    }

#undef WINDOW
#undef MFMA16
#undef DSREAD_B
#undef DSREAD_A
#undef STAGE_B
#undef STAGE_A

    // Epilogue: bias + activation, native-layout 8B stores (512B/wave/instr).
    const int cls = nblk % 3;                      // 0=f,1=o,2=z (wave-uniform)
    _Float16* gb = gates + ((size_t)((bm * 6 + nblk) * 8 + w)) * 8192 + lane * 4;
#pragma unroll
    for (int ni = 0; ni < 4; ++ni) {
        const float bias = bc[n0 + (ni >> 1) * 128 + wcl * 32 + (ni & 1) * 16 + l16];
#pragma unroll
        for (int mi = 0; mi < 8; ++mi) {
            half4 hv;
#pragma unroll
            for (int rr = 0; rr < 4; ++rr) {
                float v = acc[mi][ni][rr] + bias;
                v = (cls == 2) ? fast_tanh(v) : fast_sigmoid(v);
                hv[rr] = (_Float16)v;
            }
            *(half4*)(gb + (ni * 8 + mi) * 256) = hv;
        }
    }
}

// ---------------------------------------------------------------------------
// scan_chunks (phase A): thread = one channel, block = one (chunk,b,dir).
// Reads f,z in native layout (8B = 4 consecutive t per load), composes the
// chunk affine map c_out = P*c_in + W.
__global__ void scan_chunks(const _Float16* __restrict__ gates,
                            float2* __restrict__ PW) {
    const int d = threadIdx.x;                       // channel 0..255
    const int s = blockIdx.x, b = blockIdx.y, dir = blockIdx.z;
    const int onf = gate_noff(dir * 768 + d);
    const int onz = gate_noff(dir * 768 + 512 + d);
    float P = 1.f, W = 0.f;
    if (dir == 0) {
#pragma unroll
        for (int gi = 0; gi < 8; gi++) {
            int t = s * CHUNK + gi * 4;
            int ot = gate_toff(b, t);
            half4 f4 = *(const half4*)(gates + ot + onf);
            half4 z4 = *(const half4*)(gates + ot + onz);
#pragma unroll
            for (int u = 0; u < 4; u++) {
                float f = (float)f4[u], z = (float)z4[u];
                W = f * W + (1.f - f) * z;
                P *= f;
            }
        }
    } else {
#pragma unroll
        for (int gi = 7; gi >= 0; gi--) {
            int t = s * CHUNK + gi * 4;
            int ot = gate_toff(b, t);
            half4 f4 = *(const half4*)(gates + ot + onf);
            half4 z4 = *(const half4*)(gates + ot + onz);
#pragma unroll
            for (int u = 3; u >= 0; u--) {
                float f = (float)f4[u], z = (float)z4[u];
                W = f * W + (1.f - f) * z;
                P *= f;
            }
        }
    }
    PW[(((size_t)(dir * 8 + b)) * NCHUNK + s) * 256 + d] = make_float2(P, W);
}

// ---------------------------------------------------------------------------
// scan_seq (phase B): sequential scan over NCHUNK=128 chunks.
__global__ void scan_seq(const float2* __restrict__ PW, float* __restrict__ C0) {
    const int c = threadIdx.x;
    const int dir = blockIdx.x >> 3, b = blockIdx.x & 7;
    const size_t base = ((size_t)(dir * 8 + b)) * NCHUNK * 256 + c;
    float cc = 0.f;
    if (dir == 0) {
#pragma unroll 16
        for (int s = 0; s < NCHUNK; s++) {
            float2 pw = PW[base + (size_t)s * 256];
            C0[base + (size_t)s * 256] = cc;
            cc = pw.x * cc + pw.y;
        }
    } else {
#pragma unroll 16
        for (int s = NCHUNK - 1; s >= 0; s--) {
            float2 pw = PW[base + (size_t)s * 256];
            C0[base + (size_t)s * 256] = cc;
            cc = pw.x * cc + pw.y;
        }
    }
}

// ---------------------------------------------------------------------------
// scan_final (phase C): thread = one channel, block = one (chunk,b,dir).
// Replays the chunk from C0; h values round-trip through a 4KB LDS tile per
// 4-t group so the global store is [t][ch]-contiguous float4 per lane.
__global__ void scan_final(const _Float16* __restrict__ gates,
                           const float* __restrict__ C0,
                           float* __restrict__ out) {
    __shared__ float hbuf[4][256];
    const int d = threadIdx.x;
    const int s = blockIdx.x, b = blockIdx.y, dir = blockIdx.z;
    const int onf = gate_noff(dir * 768 + d);
    const int ono = gate_noff(dir * 768 + 256 + d);
    const int onz = gate_noff(dir * 768 + 512 + d);
    float c = C0[(((size_t)(dir * 8 + b)) * NCHUNK + s) * 256 + d];
    float* ob = out + (size_t)(b * L_) * (2 * DOUT) + dir * DOUT;
    float* lasth = out + (size_t)B_ * L_ * (2 * DOUT);
    float* lastc = lasth + B_ * (2 * DOUT);
    const int tl = d >> 6, cl = (d & 63) * 4;    // output-store mapping

    for (int gg = 0; gg < 8; gg++) {
        int gi = (dir == 0) ? gg : 7 - gg;
        int t = s * CHUNK + gi * 4;
        int ot = gate_toff(b, t);
        half4 f4 = *(const half4*)(gates + ot + onf);
        half4 o4 = *(const half4*)(gates + ot + ono);
        half4 z4 = *(const half4*)(gates + ot + onz);
        float h[4];
        if (dir == 0) {
#pragma unroll
            for (int u = 0; u < 4; u++) {
                float f = (float)f4[u], z = (float)z4[u];
                c = f * c + (1.f - f) * z;
                h[u] = c * (float)o4[u];
            }
            if (s == NCHUNK - 1 && gi == 7) {
                lasth[b * 2 * DOUT + d] = h[3];
                lastc[b * 2 * DOUT + d] = c;
            }
        } else {
#pragma unroll
            for (int u = 3; u >= 0; u--) {
                float f = (float)f4[u], z = (float)z4[u];
                c = f * c + (1.f - f) * z;
                h[u] = c * (float)o4[u];
                if (u == 3 && s == NCHUNK - 1 && gi == 7) {
                    lasth[b * 2 * DOUT + DOUT + d] = h[3];
                    lastc[b * 2 * DOUT + DOUT + d] = c;
                }
            }
        }
        hbuf[0][d] = h[0];
        hbuf[1][d] = h[1];
        hbuf[2][d] = h[2];
        hbuf[3][d] = h[3];
        __syncthreads();
        *(float4*)&ob[(size_t)(t + tl) * (2 * DOUT) + cl] = *(float4*)&hbuf[tl][cl];
        __syncthreads();
    }
}

// ---------------------------------------------------------------------------
extern "C" void kernel_launch(void* const* d_in, const int* in_sizes, int n_in,
                              void* d_out, int out_size, void* d_ws, size_t ws_size,
                              hipStream_t stream) {
    const float* x   = (const float*)d_in[0];
    // d_in[1] = lengths (unused by the reference computation)
    const float* Wf  = (const float*)d_in[2];
    const float* bfv = (const float*)d_in[3];
    const float* Wb  = (const float*)d_in[4];
    const float* bbv = (const float*)d_in[5];

    char* ws = (char*)d_ws;
    // Workspace layout (bytes):
    //   Xp    bf16  B*(L+2)*256          = 16,785,408   (offset 0; dead after GEMM)
    //   Wc    bf16  1536*768             =  2,359,296   (offset 16,785,408)
    //   bc    f32   1536                 =      6,144   (offset 19,144,704)
    //   gates fp16  B*L*1536             = 100,663,296  (offset 19,150,848, native layout)
    //   PW    f32x2 2*8*128*256          =  4,194,304   (offset 0 — reuses Xp)
    //   C0    f32   2*8*128*256          =  2,097,152   (offset 4,194,304 — reuses Xp)
    unsigned short* Xp    = (unsigned short*)(ws);
    unsigned short* Wc    = (unsigned short*)(ws + 16785408);
    float*          bc    = (float*)(ws + 19144704);
    _Float16*       gates = (_Float16*)(ws + 19150848);
    float2*         PW    = (float2*)(ws);              // reuse Xp region
    float*          C0    = (float*)(ws + 4194304);     // reuse Xp region
    float*          out   = (float*)d_out;

    prep_all<<<NXB + NWB, 256, 0, stream>>>(x, Xp, Wf, bfv, Wb, bbv, Wc, bc);
    gemm_gates<<<768, 512, 0, stream>>>(Xp, Wc, bc, gates);
    scan_chunks<<<dim3(NCHUNK, B_, 2), 256, 0, stream>>>(gates, PW);
    scan_seq<<<16, 256, 0, stream>>>(PW, C0);
    scan_final<<<dim3(NCHUNK, B_, 2), 256, 0, stream>>>(gates, C0, out);
}